// Round 3
// baseline (321.153 us; speedup 1.0000x reference)
//
#include <hip/hip_runtime.h>

#define NB 131072
#define NEG9 -1e9f

typedef __attribute__((ext_vector_type(8))) __bf16 bf16x8;
typedef __attribute__((ext_vector_type(4))) float f32x4;
typedef __attribute__((ext_vector_type(2))) unsigned int u32x2;
typedef __attribute__((ext_vector_type(4))) unsigned int u32x4;

__device__ __forceinline__ f32x4 mfma16(bf16x8 a, bf16x8 b, f32x4 c) {
    return __builtin_amdgcn_mfma_f32_16x16x32_bf16(a, b, c, 0, 0, 0);
}

// pack two floats to bf16x2 (truncation) in ONE v_perm_b32: result = [hi16(h) | hi16(l)]
__device__ __forceinline__ unsigned pk(float h, float l) {
    return __builtin_amdgcn_perm(__builtin_bit_cast(unsigned, h),
                                 __builtin_bit_cast(unsigned, l), 0x07060302u);
}

// float -> bf16 (RNE) for weight prep
__device__ __forceinline__ unsigned short f2bf(float f) {
    unsigned u = __builtin_bit_cast(unsigned, f);
    u += 0x7fffu + ((u >> 16) & 1u);
    return (unsigned short)(u >> 16);
}

// BN-folded, transposed (n-major, k-contiguous) bf16 weights + fp32 biases.
struct __align__(16) Wspace {
    unsigned short W0t[512][64];
    unsigned short W1t[256][512];
    unsigned short nW1t[64][256];
    unsigned short dW1t[64][256];
    unsigned short nW2t[128][64];
    unsigned short dW2t[128][64];
    float c0[512];
    float c1[256];
    float nb1c[64], db1c[64];
    float nb2c[128], db2c[128];
};

__device__ Wspace g_ws;

__global__ void prep_kernel(
    const float* __restrict__ W0, const float* __restrict__ b0,
    const float* __restrict__ g0, const float* __restrict__ be0,
    const float* __restrict__ rm0, const float* __restrict__ rv0,
    const float* __restrict__ W1, const float* __restrict__ b1,
    const float* __restrict__ g1, const float* __restrict__ be1,
    const float* __restrict__ rm1, const float* __restrict__ rv1,
    const float* __restrict__ nW1, const float* __restrict__ nb1,
    const float* __restrict__ nW2, const float* __restrict__ nb2,
    const float* __restrict__ dW1, const float* __restrict__ db1,
    const float* __restrict__ dW2, const float* __restrict__ db2)
{
    const int tid = blockIdx.x * 256 + threadIdx.x;  // 0 .. 131071

    {   // W1t [256][512]: n = tid>>9, k = tid&511 (coalesced writes)
        int n = tid >> 9, k = tid & 511;
        float s = g1[n] * rsqrtf(rv1[n] + 1e-5f);
        ((unsigned short*)g_ws.W1t)[tid] = f2bf(W1[k * 256 + n] * s);
    }
    if (tid < 512 * 64) {  // W0t [512][64]
        int n = tid >> 6, k = tid & 63;
        float s = g0[n] * rsqrtf(rv0[n] + 1e-5f);
        ((unsigned short*)g_ws.W0t)[tid] = f2bf(W0[k * 512 + n] * s);
    }
    if (tid < 64 * 256) {  // nW1t/dW1t [64][256]
        int n = tid >> 8, k = tid & 255;
        ((unsigned short*)g_ws.nW1t)[tid] = f2bf(nW1[k * 64 + n]);
        ((unsigned short*)g_ws.dW1t)[tid] = f2bf(dW1[k * 64 + n]);
    }
    if (tid < 128 * 64) {  // nW2t/dW2t [128][64]
        int n = tid >> 6, k = tid & 63;
        ((unsigned short*)g_ws.nW2t)[tid] = f2bf(nW2[k * 128 + n]);
        ((unsigned short*)g_ws.dW2t)[tid] = f2bf(dW2[k * 128 + n]);
    }
    if (tid < 512) g_ws.c0[tid] = (b0[tid] - rm0[tid]) * (g0[tid] * rsqrtf(rv0[tid] + 1e-5f)) + be0[tid];
    if (tid < 256) g_ws.c1[tid] = (b1[tid] - rm1[tid]) * (g1[tid] * rsqrtf(rv1[tid] + 1e-5f)) + be1[tid];
    if (tid < 64) { g_ws.nb1c[tid] = nb1[tid]; g_ws.db1c[tid] = db1[tid]; }
    if (tid < 128) { g_ws.nb2c[tid] = nb2[tid]; g_ws.db2c[tid] = db2[tid]; }
}

// 1 block = 4 waves = 64 rows. Swapped-operand MFMA: lane holds row=lane&15,
// 4 consecutive cols q*4+r -> b64 LDS writes, dwordx4 stores.
// Granule-major LDS [k/8][row][8]: conflict-free, no padding.
// LDS = 32768 (H0chunk/H1/Aheads) + 8192 (X) = 40960 -> 4 blocks/CU.
__global__ __launch_bounds__(256, 4) void fused_mlp(
    const float4* __restrict__ x4, float* __restrict__ out)
{
    __shared__ __align__(16) unsigned short sBig[32 * 64 * 8];  // 32 KB
    __shared__ __align__(16) unsigned short sXs[8 * 64 * 8];    // 8 KB

    const float* xf = (const float*)x4;
    const int tid = threadIdx.x;
    const int w = tid >> 6;
    const int lane = tid & 63;
    const int m = lane & 15;
    const int q = lane >> 4;
    const int qh = q >> 1;          // which 16B granule-half of a 32-col span
    const int ql = (q & 1) * 4;     // elem offset within granule
    const int row0 = blockIdx.x * 64;

    // ---- stage X: granule-major [g][r][8], packed via v_perm truncation ----
    for (int it = 0; it < 2; ++it) {
        int i = it * 256 + tid;            // 0..511 = 64 rows x 8 granules
        int g = i & 7, r = i >> 3;
        float4 v0 = x4[(size_t)(row0 + r) * 16 + g * 2];
        float4 v1 = x4[(size_t)(row0 + r) * 16 + g * 2 + 1];
        u32x4 p = { pk(v0.y, v0.x), pk(v0.w, v0.z), pk(v1.y, v1.x), pk(v1.w, v1.z) };
        *(u32x4*)&sXs[(g * 64 + r) * 8] = p;
    }
    __syncthreads();

    // ---- layers 0+1, 2 K-chunks of 256; layer-1 partials in regs ----
    f32x4 acc1[4][4];  // [nt][mt]: wave w owns H1 cols [w*64, +64)
#pragma unroll
    for (int a = 0; a < 4; ++a)
#pragma unroll
        for (int b = 0; b < 4; ++b) acc1[a][b] = f32x4{0.f, 0.f, 0.f, 0.f};

    for (int ch = 0; ch < 2; ++ch) {
        // layer0: wave w computes H0 cols [ch*256 + w*64, +64) for 64 rows
#pragma unroll
        for (int nt = 0; nt < 4; ++nt) {
            const int gcb = ch * 256 + w * 64 + nt * 16;
            bf16x8 wa0 = *(const bf16x8*)&g_ws.W0t[gcb + m][q * 8];
            bf16x8 wa1 = *(const bf16x8*)&g_ws.W0t[gcb + m][32 + q * 8];
            f32x4 bias = *(const f32x4*)&g_ws.c0[gcb + q * 4];
            const int lgb = w * 8 + nt * 2 + qh;   // local granule
#pragma unroll
            for (int mt = 0; mt < 4; ++mt) {
                bf16x8 xq0 = *(const bf16x8*)&sXs[(q * 64 + mt * 16 + m) * 8];
                bf16x8 xq1 = *(const bf16x8*)&sXs[((4 + q) * 64 + mt * 16 + m) * 8];
                f32x4 c = {0.f, 0.f, 0.f, 0.f};
                c = mfma16(wa0, xq0, c);
                c = mfma16(wa1, xq1, c);
                u32x2 pw = { pk(fmaxf(c[1] + bias[1], 0.f), fmaxf(c[0] + bias[0], 0.f)),
                             pk(fmaxf(c[3] + bias[3], 0.f), fmaxf(c[2] + bias[2], 0.f)) };
                *(u32x2*)&sBig[(lgb * 64 + mt * 16 + m) * 8 + ql] = pw;
            }
        }
        __syncthreads();

        // layer1 partial: 16 independent accum tiles
#pragma unroll
        for (int ks = 0; ks < 8; ++ks) {
            bf16x8 wb[4], ab[4];
#pragma unroll
            for (int nt = 0; nt < 4; ++nt)
                wb[nt] = *(const bf16x8*)&g_ws.W1t[w * 64 + nt * 16 + m][ch * 256 + ks * 32 + q * 8];
#pragma unroll
            for (int mt = 0; mt < 4; ++mt)
                ab[mt] = *(const bf16x8*)&sBig[((ks * 4 + q) * 64 + mt * 16 + m) * 8];
#pragma unroll
            for (int nt = 0; nt < 4; ++nt)
#pragma unroll
                for (int mt = 0; mt < 4; ++mt)
                    acc1[nt][mt] = mfma16(wb[nt], ab[mt], acc1[nt][mt]);
        }
        __syncthreads();
    }

    // ---- H1 = relu(acc1 + c1) -> sBig granules 0..31 ----
#pragma unroll
    for (int nt = 0; nt < 4; ++nt) {
        const int cb = w * 64 + nt * 16;
        f32x4 bias = *(const f32x4*)&g_ws.c1[cb + q * 4];
        const int gb = (cb >> 3) + qh;
#pragma unroll
        for (int mt = 0; mt < 4; ++mt) {
            f32x4 c = acc1[nt][mt];
            u32x2 pw = { pk(fmaxf(c[1] + bias[1], 0.f), fmaxf(c[0] + bias[0], 0.f)),
                         pk(fmaxf(c[3] + bias[3], 0.f), fmaxf(c[2] + bias[2], 0.f)) };
            *(u32x2*)&sBig[(gb * 64 + mt * 16 + m) * 8 + ql] = pw;
        }
    }
    __syncthreads();

    // ---- head layer 1 (both heads), accumulators stay in regs across barrier ----
    f32x4 aN[4], aD[4];
#pragma unroll
    for (int b = 0; b < 4; ++b) { aN[b] = f32x4{0.f, 0.f, 0.f, 0.f}; aD[b] = f32x4{0.f, 0.f, 0.f, 0.f}; }
#pragma unroll
    for (int ks = 0; ks < 8; ++ks) {
        bf16x8 wn = *(const bf16x8*)&g_ws.nW1t[w * 16 + m][ks * 32 + q * 8];
        bf16x8 wd = *(const bf16x8*)&g_ws.dW1t[w * 16 + m][ks * 32 + q * 8];
#pragma unroll
        for (int mt = 0; mt < 4; ++mt) {
            bf16x8 ab = *(const bf16x8*)&sBig[((ks * 4 + q) * 64 + mt * 16 + m) * 8];
            aN[mt] = mfma16(wn, ab, aN[mt]);
            aD[mt] = mfma16(wd, ab, aD[mt]);
        }
    }
    __syncthreads();  // all H1 reads done; H1 region reusable

    // ---- write head activations: nurse -> granules 0..7, doctor -> 8..15 ----
    {
        f32x4 bn = *(const f32x4*)&g_ws.nb1c[w * 16 + q * 4];
        f32x4 bd = *(const f32x4*)&g_ws.db1c[w * 16 + q * 4];
        const int gn = w * 2 + qh;
#pragma unroll
        for (int mt = 0; mt < 4; ++mt) {
            f32x4 c = aN[mt];
            u32x2 pw = { pk(fmaxf(c[1] + bn[1], 0.f), fmaxf(c[0] + bn[0], 0.f)),
                         pk(fmaxf(c[3] + bn[3], 0.f), fmaxf(c[2] + bn[2], 0.f)) };
            *(u32x2*)&sBig[(gn * 64 + mt * 16 + m) * 8 + ql] = pw;
            c = aD[mt];
            u32x2 pd = { pk(fmaxf(c[1] + bd[1], 0.f), fmaxf(c[0] + bd[0], 0.f)),
                         pk(fmaxf(c[3] + bd[3], 0.f), fmaxf(c[2] + bd[2], 0.f)) };
            *(u32x2*)&sBig[((8 + gn) * 64 + mt * 16 + m) * 8 + ql] = pd;
        }
    }
    __syncthreads();

    // ---- head layer 2 + mask + dwordx4 stores ----
    int thrN[4], thrD[4];
#pragma unroll
    for (int mt = 0; mt < 4; ++mt) {
        size_t rb = (size_t)(row0 + mt * 16 + m) * 64;
        thrN[mt] = (int)xf[rb + 60];
        thrD[mt] = (int)xf[rb + 61];
    }
#pragma unroll
    for (int head = 0; head < 2; ++head) {
        const unsigned short (*W2)[64] = head ? g_ws.dW2t : g_ws.nW2t;
        const float* b2 = head ? g_ws.db2c : g_ws.nb2c;
        const int gbase = head ? 8 : 0;
        const int* thr = head ? thrD : thrN;
        float* op = out + (size_t)head * (size_t)NB * 128;
#pragma unroll
        for (int ct = 0; ct < 2; ++ct) {
            const int cb = w * 32 + ct * 16;
            bf16x8 w0 = *(const bf16x8*)&W2[cb + m][q * 8];
            bf16x8 w1 = *(const bf16x8*)&W2[cb + m][32 + q * 8];
            f32x4 bias = *(const f32x4*)&b2[cb + q * 4];
#pragma unroll
            for (int mt = 0; mt < 4; ++mt) {
                bf16x8 a0 = *(const bf16x8*)&sBig[((gbase + q) * 64 + mt * 16 + m) * 8];
                bf16x8 a1 = *(const bf16x8*)&sBig[((gbase + 4 + q) * 64 + mt * 16 + m) * 8];
                f32x4 c = {0.f, 0.f, 0.f, 0.f};
                c = mfma16(w0, a0, c);
                c = mfma16(w1, a1, c);
                const int ci = cb + q * 4;
                const int t = thr[mt];
                float4 v;
                v.x = (ci + 0 <= t) ? c[0] + bias[0] : NEG9;
                v.y = (ci + 1 <= t) ? c[1] + bias[1] : NEG9;
                v.z = (ci + 2 <= t) ? c[2] + bias[2] : NEG9;
                v.w = (ci + 3 <= t) ? c[3] + bias[3] : NEG9;
                *(float4*)&op[(size_t)(row0 + mt * 16 + m) * 128 + ci] = v;
            }
        }
    }
}

extern "C" void kernel_launch(void* const* d_in, const int* in_sizes, int n_in,
                              void* d_out, int out_size, void* d_ws, size_t ws_size,
                              hipStream_t stream) {
    (void)in_sizes; (void)n_in; (void)d_ws; (void)ws_size;

    prep_kernel<<<512, 256, 0, stream>>>(
        (const float*)d_in[1], (const float*)d_in[2], (const float*)d_in[3],
        (const float*)d_in[4], (const float*)d_in[5], (const float*)d_in[6],
        (const float*)d_in[7], (const float*)d_in[8], (const float*)d_in[9],
        (const float*)d_in[10], (const float*)d_in[11], (const float*)d_in[12],
        (const float*)d_in[13], (const float*)d_in[14], (const float*)d_in[15],
        (const float*)d_in[16], (const float*)d_in[17], (const float*)d_in[18],
        (const float*)d_in[19], (const float*)d_in[20]);

    fused_mlp<<<NB / 64, 256, 0, stream>>>((const float4*)d_in[0], (float*)d_out);
}

// Round 4
// 293.444 us; speedup vs baseline: 1.0944x; 1.0944x over previous
//
#include <hip/hip_runtime.h>

#define NB 131072
#define NEG9 -1e9f

typedef __attribute__((ext_vector_type(8))) __bf16 bf16x8;
typedef __attribute__((ext_vector_type(4))) float f32x4;
typedef __attribute__((ext_vector_type(2))) unsigned int u32x2;
typedef __attribute__((ext_vector_type(4))) unsigned int u32x4;

__device__ __forceinline__ f32x4 mfma16(bf16x8 a, bf16x8 b, f32x4 c) {
    return __builtin_amdgcn_mfma_f32_16x16x32_bf16(a, b, c, 0, 0, 0);
}

// pack two floats to bf16x2 (truncation) in ONE v_perm_b32: [hi16(h) | hi16(l)]
__device__ __forceinline__ unsigned pk(float h, float l) {
    return __builtin_amdgcn_perm(__builtin_bit_cast(unsigned, h),
                                 __builtin_bit_cast(unsigned, l), 0x07060302u);
}
__device__ __forceinline__ unsigned pku(unsigned h, unsigned l) {
    return __builtin_amdgcn_perm(h, l, 0x07060302u);
}

// float -> bf16 (RNE) for weight prep
__device__ __forceinline__ unsigned short f2bf(float f) {
    unsigned u = __builtin_bit_cast(unsigned, f);
    u += 0x7fffu + ((u >> 16) & 1u);
    return (unsigned short)(u >> 16);
}

// BN-folded, transposed (n-major, k-contiguous) bf16 weights + fp32 biases.
struct __align__(16) Wspace {
    unsigned short W0t[512][64];
    unsigned short W1t[256][512];
    unsigned short nW1t[64][256];
    unsigned short dW1t[64][256];
    unsigned short nW2t[128][64];
    unsigned short dW2t[128][64];
    float c0[512];
    float c1[256];
    float nb1c[64], db1c[64];
    float nb2c[128], db2c[128];
};

__device__ Wspace g_ws;

__global__ void prep_kernel(
    const float* __restrict__ W0, const float* __restrict__ b0,
    const float* __restrict__ g0, const float* __restrict__ be0,
    const float* __restrict__ rm0, const float* __restrict__ rv0,
    const float* __restrict__ W1, const float* __restrict__ b1,
    const float* __restrict__ g1, const float* __restrict__ be1,
    const float* __restrict__ rm1, const float* __restrict__ rv1,
    const float* __restrict__ nW1, const float* __restrict__ nb1,
    const float* __restrict__ nW2, const float* __restrict__ nb2,
    const float* __restrict__ dW1, const float* __restrict__ db1,
    const float* __restrict__ dW2, const float* __restrict__ db2)
{
    const int tid = blockIdx.x * 256 + threadIdx.x;  // 0 .. 131071

    {   // W1t [256][512]: n = tid>>9, k = tid&511 (coalesced writes)
        int n = tid >> 9, k = tid & 511;
        float s = g1[n] * rsqrtf(rv1[n] + 1e-5f);
        ((unsigned short*)g_ws.W1t)[tid] = f2bf(W1[k * 256 + n] * s);
    }
    if (tid < 512 * 64) {  // W0t [512][64]
        int n = tid >> 6, k = tid & 63;
        float s = g0[n] * rsqrtf(rv0[n] + 1e-5f);
        ((unsigned short*)g_ws.W0t)[tid] = f2bf(W0[k * 512 + n] * s);
    }
    if (tid < 64 * 256) {  // nW1t/dW1t [64][256]
        int n = tid >> 8, k = tid & 255;
        ((unsigned short*)g_ws.nW1t)[tid] = f2bf(nW1[k * 64 + n]);
        ((unsigned short*)g_ws.dW1t)[tid] = f2bf(dW1[k * 64 + n]);
    }
    if (tid < 128 * 64) {  // nW2t/dW2t [128][64]
        int n = tid >> 6, k = tid & 63;
        ((unsigned short*)g_ws.nW2t)[tid] = f2bf(nW2[k * 128 + n]);
        ((unsigned short*)g_ws.dW2t)[tid] = f2bf(dW2[k * 128 + n]);
    }
    if (tid < 512) g_ws.c0[tid] = (b0[tid] - rm0[tid]) * (g0[tid] * rsqrtf(rv0[tid] + 1e-5f)) + be0[tid];
    if (tid < 256) g_ws.c1[tid] = (b1[tid] - rm1[tid]) * (g1[tid] * rsqrtf(rv1[tid] + 1e-5f)) + be1[tid];
    if (tid < 64) { g_ws.nb1c[tid] = nb1[tid]; g_ws.db1c[tid] = db1[tid]; }
    if (tid < 128) { g_ws.nb2c[tid] = nb2[tid]; g_ws.db2c[tid] = db2[tid]; }
}

// 1 block = 4 waves = 64 rows. Swapped-operand MFMA: lane holds row=lane&15,
// 4 consecutive cols q*4+r -> b64 LDS writes, dwordx4 nontemporal stores.
// Granule-major LDS [k/8][row][8]: conflict-minimal, no padding.
// LDS = 40960 B; launch_bounds(256,3): 170-reg budget, NO spills (r3 lesson:
// (256,4) => 128-reg budget => scratch spills => +100 MB HBM traffic).
__global__ __launch_bounds__(256, 3) void fused_mlp(
    const float4* __restrict__ x4, float* __restrict__ out)
{
    __shared__ __align__(16) unsigned short sBig[32 * 64 * 8];  // 32 KB
    __shared__ __align__(16) unsigned short sXs[8 * 64 * 8];    // 8 KB (X, live to end)

    const int tid = threadIdx.x;
    const int w = tid >> 6;
    const int lane = tid & 63;
    const int m = lane & 15;
    const int q = lane >> 4;
    const int qh = q >> 1;
    const int ql = (q & 1) * 4;
    const int row0 = blockIdx.x * 64;

    // ---- stage X: granule-major [g][r][8], nontemporal loads, v_perm pack ----
    const u32x4* xu = (const u32x4*)x4;
    for (int it = 0; it < 2; ++it) {
        int i = it * 256 + tid;            // 0..511 = 64 rows x 8 granules
        int g = i & 7, r = i >> 3;
        u32x4 v0 = __builtin_nontemporal_load(&xu[(size_t)(row0 + r) * 16 + g * 2]);
        u32x4 v1 = __builtin_nontemporal_load(&xu[(size_t)(row0 + r) * 16 + g * 2 + 1]);
        u32x4 p = { pku(v0[1], v0[0]), pku(v0[3], v0[2]), pku(v1[1], v1[0]), pku(v1[3], v1[2]) };
        *(u32x4*)&sXs[(g * 64 + r) * 8] = p;
    }
    __syncthreads();

    // ---- layers 0+1, 2 K-chunks of 256; layer-1 partials in regs (AGPRs) ----
    f32x4 acc1[4][4];
#pragma unroll
    for (int a = 0; a < 4; ++a)
#pragma unroll
        for (int b = 0; b < 4; ++b) acc1[a][b] = f32x4{0.f, 0.f, 0.f, 0.f};

    for (int ch = 0; ch < 2; ++ch) {
        // layer0: wave w computes H0 cols [ch*256 + w*64, +64) for 64 rows
#pragma unroll
        for (int nt = 0; nt < 4; ++nt) {
            const int gcb = ch * 256 + w * 64 + nt * 16;
            bf16x8 wa0 = *(const bf16x8*)&g_ws.W0t[gcb + m][q * 8];
            bf16x8 wa1 = *(const bf16x8*)&g_ws.W0t[gcb + m][32 + q * 8];
            f32x4 bias = *(const f32x4*)&g_ws.c0[gcb + q * 4];
            const int lgb = w * 8 + nt * 2 + qh;
#pragma unroll
            for (int mt = 0; mt < 4; ++mt) {
                bf16x8 xq0 = *(const bf16x8*)&sXs[(q * 64 + mt * 16 + m) * 8];
                bf16x8 xq1 = *(const bf16x8*)&sXs[((4 + q) * 64 + mt * 16 + m) * 8];
                f32x4 c = {0.f, 0.f, 0.f, 0.f};
                c = mfma16(wa0, xq0, c);
                c = mfma16(wa1, xq1, c);
                u32x2 pw = { pk(fmaxf(c[1] + bias[1], 0.f), fmaxf(c[0] + bias[0], 0.f)),
                             pk(fmaxf(c[3] + bias[3], 0.f), fmaxf(c[2] + bias[2], 0.f)) };
                *(u32x2*)&sBig[(lgb * 64 + mt * 16 + m) * 8 + ql] = pw;
            }
        }
        __syncthreads();

        // layer1 partial: 16 independent accumulator tiles
#pragma unroll
        for (int ks = 0; ks < 8; ++ks) {
            bf16x8 wb[4], ab[4];
#pragma unroll
            for (int nt = 0; nt < 4; ++nt)
                wb[nt] = *(const bf16x8*)&g_ws.W1t[w * 64 + nt * 16 + m][ch * 256 + ks * 32 + q * 8];
#pragma unroll
            for (int mt = 0; mt < 4; ++mt)
                ab[mt] = *(const bf16x8*)&sBig[((ks * 4 + q) * 64 + mt * 16 + m) * 8];
#pragma unroll
            for (int nt = 0; nt < 4; ++nt)
#pragma unroll
                for (int mt = 0; mt < 4; ++mt)
                    acc1[nt][mt] = mfma16(wb[nt], ab[mt], acc1[nt][mt]);
        }
        __syncthreads();
    }

    // ---- H1 = relu(acc1 + c1) -> sBig granules 0..31 ----
#pragma unroll
    for (int nt = 0; nt < 4; ++nt) {
        const int cb = w * 64 + nt * 16;
        f32x4 bias = *(const f32x4*)&g_ws.c1[cb + q * 4];
        const int gb = (cb >> 3) + qh;
#pragma unroll
        for (int mt = 0; mt < 4; ++mt) {
            f32x4 c = acc1[nt][mt];
            u32x2 pw = { pk(fmaxf(c[1] + bias[1], 0.f), fmaxf(c[0] + bias[0], 0.f)),
                         pk(fmaxf(c[3] + bias[3], 0.f), fmaxf(c[2] + bias[2], 0.f)) };
            *(u32x2*)&sBig[(gb * 64 + mt * 16 + m) * 8 + ql] = pw;
        }
    }
    __syncthreads();

    // ---- head layer 1 (both heads), accumulators in regs across barrier ----
    f32x4 aN[4], aD[4];
#pragma unroll
    for (int b = 0; b < 4; ++b) { aN[b] = f32x4{0.f, 0.f, 0.f, 0.f}; aD[b] = f32x4{0.f, 0.f, 0.f, 0.f}; }
#pragma unroll
    for (int ks = 0; ks < 8; ++ks) {
        bf16x8 wn = *(const bf16x8*)&g_ws.nW1t[w * 16 + m][ks * 32 + q * 8];
        bf16x8 wd = *(const bf16x8*)&g_ws.dW1t[w * 16 + m][ks * 32 + q * 8];
#pragma unroll
        for (int mt = 0; mt < 4; ++mt) {
            bf16x8 ab = *(const bf16x8*)&sBig[((ks * 4 + q) * 64 + mt * 16 + m) * 8];
            aN[mt] = mfma16(wn, ab, aN[mt]);
            aD[mt] = mfma16(wd, ab, aD[mt]);
        }
    }
    __syncthreads();  // all H1 reads done; H1 region reusable

    // ---- write head activations: nurse -> granules 0..7, doctor -> 8..15 ----
    {
        f32x4 bn = *(const f32x4*)&g_ws.nb1c[w * 16 + q * 4];
        f32x4 bd = *(const f32x4*)&g_ws.db1c[w * 16 + q * 4];
        const int gn = w * 2 + qh;
#pragma unroll
        for (int mt = 0; mt < 4; ++mt) {
            f32x4 c = aN[mt];
            u32x2 pw = { pk(fmaxf(c[1] + bn[1], 0.f), fmaxf(c[0] + bn[0], 0.f)),
                         pk(fmaxf(c[3] + bn[3], 0.f), fmaxf(c[2] + bn[2], 0.f)) };
            *(u32x2*)&sBig[(gn * 64 + mt * 16 + m) * 8 + ql] = pw;
            c = aD[mt];
            u32x2 pd = { pk(fmaxf(c[1] + bd[1], 0.f), fmaxf(c[0] + bd[0], 0.f)),
                         pk(fmaxf(c[3] + bd[3], 0.f), fmaxf(c[2] + bd[2], 0.f)) };
            *(u32x2*)&sBig[((8 + gn) * 64 + mt * 16 + m) * 8 + ql] = pd;
        }
    }
    __syncthreads();

    // ---- thresholds from sXs (cols 60,61 live in granule 7, elems 4,5; class
    // ids 0..127 are exact in bf16) -> zero extra global traffic ----
    int thrN[4], thrD[4];
#pragma unroll
    for (int mt = 0; mt < 4; ++mt) {
        unsigned tv = *(const unsigned*)&sXs[(7 * 64 + mt * 16 + m) * 8 + 4];
        thrN[mt] = (int)__builtin_bit_cast(float, tv << 16);
        thrD[mt] = (int)__builtin_bit_cast(float, tv & 0xffff0000u);
    }

    // ---- head layer 2 + mask + nontemporal dwordx4 stores ----
#pragma unroll
    for (int head = 0; head < 2; ++head) {
        const unsigned short (*W2)[64] = head ? g_ws.dW2t : g_ws.nW2t;
        const float* b2 = head ? g_ws.db2c : g_ws.nb2c;
        const int gbase = head ? 8 : 0;
        const int* thr = head ? thrD : thrN;
        float* op = out + (size_t)head * (size_t)NB * 128;
#pragma unroll
        for (int ct = 0; ct < 2; ++ct) {
            const int cb = w * 32 + ct * 16;
            bf16x8 w0 = *(const bf16x8*)&W2[cb + m][q * 8];
            bf16x8 w1 = *(const bf16x8*)&W2[cb + m][32 + q * 8];
            f32x4 bias = *(const f32x4*)&b2[cb + q * 4];
#pragma unroll
            for (int mt = 0; mt < 4; ++mt) {
                bf16x8 a0 = *(const bf16x8*)&sBig[((gbase + q) * 64 + mt * 16 + m) * 8];
                bf16x8 a1 = *(const bf16x8*)&sBig[((gbase + 4 + q) * 64 + mt * 16 + m) * 8];
                f32x4 c = {0.f, 0.f, 0.f, 0.f};
                c = mfma16(w0, a0, c);
                c = mfma16(w1, a1, c);
                const int ci = cb + q * 4;
                const int t = thr[mt];
                u32x4 v;
                v[0] = __builtin_bit_cast(unsigned, (ci + 0 <= t) ? c[0] + bias[0] : NEG9);
                v[1] = __builtin_bit_cast(unsigned, (ci + 1 <= t) ? c[1] + bias[1] : NEG9);
                v[2] = __builtin_bit_cast(unsigned, (ci + 2 <= t) ? c[2] + bias[2] : NEG9);
                v[3] = __builtin_bit_cast(unsigned, (ci + 3 <= t) ? c[3] + bias[3] : NEG9);
                __builtin_nontemporal_store(v, (u32x4*)&op[(size_t)(row0 + mt * 16 + m) * 128 + ci]);
            }
        }
    }
}

extern "C" void kernel_launch(void* const* d_in, const int* in_sizes, int n_in,
                              void* d_out, int out_size, void* d_ws, size_t ws_size,
                              hipStream_t stream) {
    (void)in_sizes; (void)n_in; (void)d_ws; (void)ws_size;

    prep_kernel<<<512, 256, 0, stream>>>(
        (const float*)d_in[1], (const float*)d_in[2], (const float*)d_in[3],
        (const float*)d_in[4], (const float*)d_in[5], (const float*)d_in[6],
        (const float*)d_in[7], (const float*)d_in[8], (const float*)d_in[9],
        (const float*)d_in[10], (const float*)d_in[11], (const float*)d_in[12],
        (const float*)d_in[13], (const float*)d_in[14], (const float*)d_in[15],
        (const float*)d_in[16], (const float*)d_in[17], (const float*)d_in[18],
        (const float*)d_in[19], (const float*)d_in[20]);

    fused_mlp<<<NB / 64, 256, 0, stream>>>((const float4*)d_in[0], (float*)d_out);
}

// Round 6
// 291.509 us; speedup vs baseline: 1.1017x; 1.0066x over previous
//
#include <hip/hip_runtime.h>

#define NB 131072
#define NEG9 -1e9f

typedef __attribute__((ext_vector_type(8))) __bf16 bf16x8;
typedef __attribute__((ext_vector_type(4))) float f32x4;
typedef __attribute__((ext_vector_type(2))) unsigned int u32x2;
typedef __attribute__((ext_vector_type(4))) unsigned int u32x4;

__device__ __forceinline__ f32x4 mfma16(bf16x8 a, bf16x8 b, f32x4 c) {
    return __builtin_amdgcn_mfma_f32_16x16x32_bf16(a, b, c, 0, 0, 0);
}

// pack two floats to bf16x2 (truncation) in ONE v_perm_b32: [hi16(h) | hi16(l)]
__device__ __forceinline__ unsigned pk(float h, float l) {
    return __builtin_amdgcn_perm(__builtin_bit_cast(unsigned, h),
                                 __builtin_bit_cast(unsigned, l), 0x07060302u);
}
__device__ __forceinline__ unsigned pku(unsigned h, unsigned l) {
    return __builtin_amdgcn_perm(h, l, 0x07060302u);
}

// float -> bf16 (RNE) for weight prep
__device__ __forceinline__ unsigned short f2bf(float f) {
    unsigned u = __builtin_bit_cast(unsigned, f);
    u += 0x7fffu + ((u >> 16) & 1u);
    return (unsigned short)(u >> 16);
}

// BN-folded, transposed (n-major, k-contiguous) bf16 weights + fp32 biases.
struct __align__(16) Wspace {
    unsigned short W0t[512][64];
    unsigned short W1t[256][512];
    unsigned short nW1t[64][256];
    unsigned short dW1t[64][256];
    unsigned short nW2t[128][64];
    unsigned short dW2t[128][64];
    float c0[512];
    float c1[256];
    float nb1c[64], db1c[64];
    float nb2c[128], db2c[128];
};

__device__ Wspace g_ws;

__global__ void prep_kernel(
    const float* __restrict__ W0, const float* __restrict__ b0,
    const float* __restrict__ g0, const float* __restrict__ be0,
    const float* __restrict__ rm0, const float* __restrict__ rv0,
    const float* __restrict__ W1, const float* __restrict__ b1,
    const float* __restrict__ g1, const float* __restrict__ be1,
    const float* __restrict__ rm1, const float* __restrict__ rv1,
    const float* __restrict__ nW1, const float* __restrict__ nb1,
    const float* __restrict__ nW2, const float* __restrict__ nb2,
    const float* __restrict__ dW1, const float* __restrict__ db1,
    const float* __restrict__ dW2, const float* __restrict__ db2)
{
    const int tid = blockIdx.x * 256 + threadIdx.x;  // 0 .. 131071

    {   // W1t [256][512]: n = tid>>9, k = tid&511 (coalesced writes)
        int n = tid >> 9, k = tid & 511;
        float s = g1[n] * rsqrtf(rv1[n] + 1e-5f);
        ((unsigned short*)g_ws.W1t)[tid] = f2bf(W1[k * 256 + n] * s);
    }
    if (tid < 512 * 64) {  // W0t [512][64]
        int n = tid >> 6, k = tid & 63;
        float s = g0[n] * rsqrtf(rv0[n] + 1e-5f);
        ((unsigned short*)g_ws.W0t)[tid] = f2bf(W0[k * 512 + n] * s);
    }
    if (tid < 64 * 256) {  // nW1t/dW1t [64][256]
        int n = tid >> 8, k = tid & 255;
        ((unsigned short*)g_ws.nW1t)[tid] = f2bf(nW1[k * 64 + n]);
        ((unsigned short*)g_ws.dW1t)[tid] = f2bf(dW1[k * 64 + n]);
    }
    if (tid < 128 * 64) {  // nW2t/dW2t [128][64]
        int n = tid >> 6, k = tid & 63;
        ((unsigned short*)g_ws.nW2t)[tid] = f2bf(nW2[k * 128 + n]);
        ((unsigned short*)g_ws.dW2t)[tid] = f2bf(dW2[k * 128 + n]);
    }
    if (tid < 512) g_ws.c0[tid] = (b0[tid] - rm0[tid]) * (g0[tid] * rsqrtf(rv0[tid] + 1e-5f)) + be0[tid];
    if (tid < 256) g_ws.c1[tid] = (b1[tid] - rm1[tid]) * (g1[tid] * rsqrtf(rv1[tid] + 1e-5f)) + be1[tid];
    if (tid < 64) { g_ws.nb1c[tid] = nb1[tid]; g_ws.db1c[tid] = db1[tid]; }
    if (tid < 128) { g_ws.nb2c[tid] = nb2[tid]; g_ws.db2c[tid] = db2[tid]; }
}

// 1 block = 8 waves = 64 rows, bf16 (r2-r4 proven numerics/mask machinery).
// Wave w: layer0 cols [w*32,+32)/chunk; layer1 cols [w*32,+32) (acc = 32 regs);
// head1: head=w>>2, 16 cols; head2: head=w>>2, 32 cols.
// H0 chunked 2x256; H1 overlays the chunk region after last read.
// LDS 57.3 KB -> 2 blocks/CU = 16 waves/CU; (512,4) = 128-reg budget (acc1
// is only 32 regs now, vs r3's 64-reg spill at the same budget).
__global__ __launch_bounds__(512, 4) void fused_mlp(
    const u32x4* __restrict__ xu, float* __restrict__ out)
{
    __shared__ __align__(16) unsigned short sXs [8 * 64 * 8];   //  8 KB (X, live to end)
    __shared__ __align__(16) unsigned short sReg[32 * 64 * 8];  // 32 KB (H0 chunk / H1)
    __shared__ __align__(16) unsigned short sAn [8 * 64 * 8];   //  8 KB
    __shared__ __align__(16) unsigned short sAd [8 * 64 * 8];   //  8 KB

    const int tid = threadIdx.x;
    const int w = tid >> 6;          // wave 0..7
    const int lane = tid & 63;
    const int m = lane & 15;
    const int q = lane >> 4;
    const int qh = q >> 1;
    const int ql = (q & 1) * 4;
    const int row0 = blockIdx.x * 64;

    // ---- stage X -> bf16 granule-major [g][r][8] (one row-granule/thread) ----
    {
        int r = tid >> 3, g = tid & 7;
        u32x4 v0 = __builtin_nontemporal_load(&xu[(size_t)(row0 + r) * 16 + g * 2]);
        u32x4 v1 = __builtin_nontemporal_load(&xu[(size_t)(row0 + r) * 16 + g * 2 + 1]);
        u32x4 p = { pku(v0[1], v0[0]), pku(v0[3], v0[2]), pku(v1[1], v1[0]), pku(v1[3], v1[2]) };
        *(u32x4*)&sXs[(g * 64 + r) * 8] = p;
    }
    __syncthreads();

    // ---- layers 0+1, 2 K-chunks of 256; layer-1 partials in regs ----
    f32x4 acc1[2][4];
#pragma unroll
    for (int a = 0; a < 2; ++a)
#pragma unroll
        for (int b = 0; b < 4; ++b) acc1[a][b] = f32x4{0.f, 0.f, 0.f, 0.f};

    for (int ch = 0; ch < 2; ++ch) {
        // layer0: wave w -> chunk cols [w*32,+32)
#pragma unroll
        for (int nt = 0; nt < 2; ++nt) {
            const int gcb = ch * 256 + w * 32 + nt * 16;
            bf16x8 wa0 = *(const bf16x8*)&g_ws.W0t[gcb + m][q * 8];
            bf16x8 wa1 = *(const bf16x8*)&g_ws.W0t[gcb + m][32 + q * 8];
            f32x4 bias = *(const f32x4*)&g_ws.c0[gcb + q * 4];
            const int kg = w * 4 + nt * 2 + qh;
#pragma unroll
            for (int mt = 0; mt < 4; ++mt) {
                bf16x8 xq0 = *(const bf16x8*)&sXs[(q * 64 + mt * 16 + m) * 8];
                bf16x8 xq1 = *(const bf16x8*)&sXs[((4 + q) * 64 + mt * 16 + m) * 8];
                f32x4 c = {0.f, 0.f, 0.f, 0.f};
                c = mfma16(wa0, xq0, c);
                c = mfma16(wa1, xq1, c);
                u32x2 pw = { pk(fmaxf(c[1] + bias[1], 0.f), fmaxf(c[0] + bias[0], 0.f)),
                             pk(fmaxf(c[3] + bias[3], 0.f), fmaxf(c[2] + bias[2], 0.f)) };
                *(u32x2*)&sReg[(kg * 64 + mt * 16 + m) * 8 + ql] = pw;
            }
        }
        __syncthreads();

        // layer1 partial: 8 independent accumulator tiles
#pragma unroll
        for (int ks = 0; ks < 8; ++ks) {
            bf16x8 wb[2], ab[4];
#pragma unroll
            for (int nt = 0; nt < 2; ++nt)
                wb[nt] = *(const bf16x8*)&g_ws.W1t[w * 32 + nt * 16 + m][ch * 256 + ks * 32 + q * 8];
#pragma unroll
            for (int mt = 0; mt < 4; ++mt)
                ab[mt] = *(const bf16x8*)&sReg[((ks * 4 + q) * 64 + mt * 16 + m) * 8];
#pragma unroll
            for (int nt = 0; nt < 2; ++nt)
#pragma unroll
                for (int mt = 0; mt < 4; ++mt)
                    acc1[nt][mt] = mfma16(wb[nt], ab[mt], acc1[nt][mt]);
        }
        __syncthreads();
    }

    // ---- H1 = relu(acc1 + c1) -> sReg (H0 region dead after last sync) ----
#pragma unroll
    for (int nt = 0; nt < 2; ++nt) {
        const int cb = w * 32 + nt * 16;
        f32x4 bias = *(const f32x4*)&g_ws.c1[cb + q * 4];
        const int kg = w * 4 + nt * 2 + qh;
#pragma unroll
        for (int mt = 0; mt < 4; ++mt) {
            f32x4 c = acc1[nt][mt];
            u32x2 pw = { pk(fmaxf(c[1] + bias[1], 0.f), fmaxf(c[0] + bias[0], 0.f)),
                         pk(fmaxf(c[3] + bias[3], 0.f), fmaxf(c[2] + bias[2], 0.f)) };
            *(u32x2*)&sReg[(kg * 64 + mt * 16 + m) * 8 + ql] = pw;
        }
    }
    __syncthreads();

    // ---- head layer 1: head = w>>2, cols (w&3)*16..+16, K=256 ----
    {
        const int head = w >> 2;
        const int cb = (w & 3) * 16;
        const unsigned short (*Wh)[256] = head ? g_ws.dW1t : g_ws.nW1t;
        const float* bh = head ? g_ws.db1c : g_ws.nb1c;
        unsigned short* Ah = head ? sAd : sAn;
        f32x4 acc[4];
#pragma unroll
        for (int b = 0; b < 4; ++b) acc[b] = f32x4{0.f, 0.f, 0.f, 0.f};
#pragma unroll
        for (int ks = 0; ks < 8; ++ks) {
            bf16x8 wh = *(const bf16x8*)&Wh[cb + m][ks * 32 + q * 8];
#pragma unroll
            for (int mt = 0; mt < 4; ++mt) {
                bf16x8 ab = *(const bf16x8*)&sReg[((ks * 4 + q) * 64 + mt * 16 + m) * 8];
                acc[mt] = mfma16(wh, ab, acc[mt]);
            }
        }
        f32x4 bias = *(const f32x4*)&bh[cb + q * 4];
        const int kg = (w & 3) * 2 + qh;
#pragma unroll
        for (int mt = 0; mt < 4; ++mt) {
            f32x4 c = acc[mt];
            u32x2 pw = { pk(fmaxf(c[1] + bias[1], 0.f), fmaxf(c[0] + bias[0], 0.f)),
                         pk(fmaxf(c[3] + bias[3], 0.f), fmaxf(c[2] + bias[2], 0.f)) };
            *(u32x2*)&Ah[(kg * 64 + mt * 16 + m) * 8 + ql] = pw;
        }
    }
    __syncthreads();

    // ---- head layer 2 + mask + plain dwordx4 stores ----
    {
        const int head = w >> 2;
        const unsigned short (*W2)[64] = head ? g_ws.dW2t : g_ws.nW2t;
        const float* b2 = head ? g_ws.db2c : g_ws.nb2c;
        const unsigned short* Ah = head ? sAd : sAn;
        float* op = out + (size_t)head * (size_t)NB * 128;

        // thresholds via r4's PROVEN sXs path: granule 7 elems 4,5 = cols 60,61
        // (class ids 0..127 exact in bf16)
        int thr[4];
#pragma unroll
        for (int mt = 0; mt < 4; ++mt) {
            unsigned tv = *(const unsigned*)&sXs[(7 * 64 + mt * 16 + m) * 8 + 4];
            thr[mt] = (int)__builtin_bit_cast(float, head ? (tv & 0xffff0000u) : (tv << 16));
        }
#pragma unroll
        for (int ct = 0; ct < 2; ++ct) {
            const int ocb = (w & 3) * 32 + ct * 16;
            bf16x8 w0 = *(const bf16x8*)&W2[ocb + m][q * 8];
            bf16x8 w1 = *(const bf16x8*)&W2[ocb + m][32 + q * 8];
            f32x4 bias = *(const f32x4*)&b2[ocb + q * 4];
#pragma unroll
            for (int mt = 0; mt < 4; ++mt) {
                bf16x8 a0 = *(const bf16x8*)&Ah[(q * 64 + mt * 16 + m) * 8];
                bf16x8 a1 = *(const bf16x8*)&Ah[((4 + q) * 64 + mt * 16 + m) * 8];
                f32x4 c = {0.f, 0.f, 0.f, 0.f};
                c = mfma16(w0, a0, c);
                c = mfma16(w1, a1, c);
                const int ci = ocb + q * 4;
                const int t = thr[mt];
                float4 v;
                v.x = (ci + 0 <= t) ? c[0] + bias[0] : NEG9;
                v.y = (ci + 1 <= t) ? c[1] + bias[1] : NEG9;
                v.z = (ci + 2 <= t) ? c[2] + bias[2] : NEG9;
                v.w = (ci + 3 <= t) ? c[3] + bias[3] : NEG9;
                *(float4*)&op[(size_t)(row0 + mt * 16 + m) * 128 + ci] = v;
            }
        }
    }
}

extern "C" void kernel_launch(void* const* d_in, const int* in_sizes, int n_in,
                              void* d_out, int out_size, void* d_ws, size_t ws_size,
                              hipStream_t stream) {
    (void)in_sizes; (void)n_in; (void)d_ws; (void)ws_size;

    prep_kernel<<<512, 256, 0, stream>>>(
        (const float*)d_in[1], (const float*)d_in[2], (const float*)d_in[3],
        (const float*)d_in[4], (const float*)d_in[5], (const float*)d_in[6],
        (const float*)d_in[7], (const float*)d_in[8], (const float*)d_in[9],
        (const float*)d_in[10], (const float*)d_in[11], (const float*)d_in[12],
        (const float*)d_in[13], (const float*)d_in[14], (const float*)d_in[15],
        (const float*)d_in[16], (const float*)d_in[17], (const float*)d_in[18],
        (const float*)d_in[19], (const float*)d_in[20]);

    fused_mlp<<<NB / 64, 512, 0, stream>>>((const u32x4*)d_in[0], (float*)d_out);
}